// Round 1
// baseline (1639.282 us; speedup 1.0000x reference)
//
#include <hip/hip_runtime.h>
#include <hip/hip_bf16.h>

#define B_ 64
#define S_ 2048
#define D_ 128
#define BQ 128         // q rows per block
#define BK 64          // k cols per tile
#define NKT (S_ / BK)  // 32 tiles
#define NW 8           // waves per block

typedef __attribute__((ext_vector_type(8))) __bf16 bf16x8;
typedef __attribute__((ext_vector_type(4))) float f32x4;

__device__ __forceinline__ __bf16 f2bf(float x) { return (__bf16)x; }

// LDS row strides padded (+8 bf16 = +16B) so 16-lane groups reading
// ds_read_b128 down rows land on distinct bank quads (2-way max, free).
#define KSTR 136   // 128 + 8
#define VSTR 72    // 64 + 8
#define PSTR 72    // 64 + 8

__global__ __launch_bounds__(512) void attn_fused(
    const float* __restrict__ Q, const float* __restrict__ K,
    const float* __restrict__ V, float* __restrict__ Out,
    float* __restrict__ Attn)
{
    __shared__ __align__(16) __bf16 Klds[BK][KSTR];       // 17408 B
    __shared__ __align__(16) __bf16 Vlds[D_][VSTR];       // 18432 B (V transposed: [d][k])
    __shared__ __align__(16) __bf16 Plds[NW][16][PSTR];   // 18432 B (per-wave P tile)

    const int b   = blockIdx.x;        // batch (fastest -> same-batch blocks adjacent)
    const int q0  = blockIdx.y * BQ;   // q-tile origin
    const int tid = threadIdx.x;
    const int w   = tid >> 6;          // wave 0..7
    const int l   = tid & 63;
    const int l15 = l & 15;
    const int lhi = l >> 4;            // 0..3

    const float scale = 0.08838834764831845f;  // 1/sqrt(128)

    const float* Qb = Q + (size_t)b * S_ * D_;
    const float* Kb = K + (size_t)b * S_ * D_;
    const float* Vb = V + (size_t)b * S_ * D_;
    float* Ob = Out  + (size_t)b * S_ * D_;
    float* Ab = Attn + (size_t)b * S_ * S_;

    // ---- Q fragments: 4 d-steps of 8 contiguous bf16, scale folded in ----
    bf16x8 qf[4];
    {
        const float* qp = Qb + (size_t)(q0 + w * 16 + l15) * D_;
        #pragma unroll
        for (int t = 0; t < 4; ++t) {
            const float4 a0 = *(const float4*)(qp + t * 32 + lhi * 8);
            const float4 a1 = *(const float4*)(qp + t * 32 + lhi * 8 + 4);
            qf[t][0] = f2bf(a0.x * scale); qf[t][1] = f2bf(a0.y * scale);
            qf[t][2] = f2bf(a0.z * scale); qf[t][3] = f2bf(a0.w * scale);
            qf[t][4] = f2bf(a1.x * scale); qf[t][5] = f2bf(a1.y * scale);
            qf[t][6] = f2bf(a1.z * scale); qf[t][7] = f2bf(a1.w * scale);
        }
    }

    const int srow = tid >> 3;         // staging row 0..63
    const int scol = (tid & 7) * 16;   // staging col 0..112

    float lsum[4] = {0.f, 0.f, 0.f, 0.f};
    const f32x4 zf = {0.f, 0.f, 0.f, 0.f};

    // ================= phase 1: denominators l = sum_k exp(s) =================
    for (int kt = 0; kt < NKT; ++kt) {
        __syncthreads();
        {
            const float* src = Kb + (size_t)(kt * BK + srow) * D_ + scol;
            float4 a0 = *(const float4*)(src + 0);
            float4 a1 = *(const float4*)(src + 4);
            float4 a2 = *(const float4*)(src + 8);
            float4 a3 = *(const float4*)(src + 12);
            bf16x8 v0, v1;
            v0[0] = f2bf(a0.x); v0[1] = f2bf(a0.y); v0[2] = f2bf(a0.z); v0[3] = f2bf(a0.w);
            v0[4] = f2bf(a1.x); v0[5] = f2bf(a1.y); v0[6] = f2bf(a1.z); v0[7] = f2bf(a1.w);
            v1[0] = f2bf(a2.x); v1[1] = f2bf(a2.y); v1[2] = f2bf(a2.z); v1[3] = f2bf(a2.w);
            v1[4] = f2bf(a3.x); v1[5] = f2bf(a3.y); v1[6] = f2bf(a3.z); v1[7] = f2bf(a3.w);
            *(bf16x8*)&Klds[srow][scol]     = v0;
            *(bf16x8*)&Klds[srow][scol + 8] = v1;
        }
        __syncthreads();

        f32x4 sacc[4] = {zf, zf, zf, zf};
        #pragma unroll
        for (int t = 0; t < 4; ++t) {
            #pragma unroll
            for (int c = 0; c < 4; ++c) {
                bf16x8 kf = *(bf16x8*)&Klds[c * 16 + l15][t * 32 + lhi * 8];
                sacc[c] = __builtin_amdgcn_mfma_f32_16x16x32_bf16(qf[t], kf, sacc[c], 0, 0, 0);
            }
        }
        #pragma unroll
        for (int c = 0; c < 4; ++c) {
            #pragma unroll
            for (int r = 0; r < 4; ++r) lsum[r] += __expf(sacc[c][r]);
        }
    }

    // reduce across the 16 lanes that share each row; result -> 1/l
    #pragma unroll
    for (int r = 0; r < 4; ++r) {
        float v = lsum[r];
        v += __shfl_xor(v, 1);
        v += __shfl_xor(v, 2);
        v += __shfl_xor(v, 4);
        v += __shfl_xor(v, 8);
        lsum[r] = 1.0f / v;
    }

    // ================= phase 2: attn writeout + PV =================
    f32x4 oacc[8] = {zf, zf, zf, zf, zf, zf, zf, zf};
    __bf16* pbase = &Plds[w][0][0];

    for (int kt = 0; kt < NKT; ++kt) {
        __syncthreads();
        {
            const float* src = Kb + (size_t)(kt * BK + srow) * D_ + scol;
            float4 a0 = *(const float4*)(src + 0);
            float4 a1 = *(const float4*)(src + 4);
            float4 a2 = *(const float4*)(src + 8);
            float4 a3 = *(const float4*)(src + 12);
            bf16x8 v0, v1;
            v0[0] = f2bf(a0.x); v0[1] = f2bf(a0.y); v0[2] = f2bf(a0.z); v0[3] = f2bf(a0.w);
            v0[4] = f2bf(a1.x); v0[5] = f2bf(a1.y); v0[6] = f2bf(a1.z); v0[7] = f2bf(a1.w);
            v1[0] = f2bf(a2.x); v1[1] = f2bf(a2.y); v1[2] = f2bf(a2.z); v1[3] = f2bf(a2.w);
            v1[4] = f2bf(a3.x); v1[5] = f2bf(a3.y); v1[6] = f2bf(a3.z); v1[7] = f2bf(a3.w);
            *(bf16x8*)&Klds[srow][scol]     = v0;
            *(bf16x8*)&Klds[srow][scol + 8] = v1;

            // V staged transposed: Vlds[d][k]
            const float* vs = Vb + (size_t)(kt * BK + srow) * D_ + scol;
            float4 b0 = *(const float4*)(vs + 0);
            float4 b1 = *(const float4*)(vs + 4);
            float4 b2 = *(const float4*)(vs + 8);
            float4 b3 = *(const float4*)(vs + 12);
            Vlds[scol +  0][srow] = f2bf(b0.x); Vlds[scol +  1][srow] = f2bf(b0.y);
            Vlds[scol +  2][srow] = f2bf(b0.z); Vlds[scol +  3][srow] = f2bf(b0.w);
            Vlds[scol +  4][srow] = f2bf(b1.x); Vlds[scol +  5][srow] = f2bf(b1.y);
            Vlds[scol +  6][srow] = f2bf(b1.z); Vlds[scol +  7][srow] = f2bf(b1.w);
            Vlds[scol +  8][srow] = f2bf(b2.x); Vlds[scol +  9][srow] = f2bf(b2.y);
            Vlds[scol + 10][srow] = f2bf(b2.z); Vlds[scol + 11][srow] = f2bf(b2.w);
            Vlds[scol + 12][srow] = f2bf(b3.x); Vlds[scol + 13][srow] = f2bf(b3.y);
            Vlds[scol + 14][srow] = f2bf(b3.z); Vlds[scol + 15][srow] = f2bf(b3.w);
        }
        __syncthreads();

        // recompute S tile (16 q-rows x 64 k)
        f32x4 sacc[4] = {zf, zf, zf, zf};
        #pragma unroll
        for (int t = 0; t < 4; ++t) {
            #pragma unroll
            for (int c = 0; c < 4; ++c) {
                bf16x8 kf = *(bf16x8*)&Klds[c * 16 + l15][t * 32 + lhi * 8];
                sacc[c] = __builtin_amdgcn_mfma_f32_16x16x32_bf16(qf[t], kf, sacc[c], 0, 0, 0);
            }
        }

        // p = exp(s) * (1/l): write attn (fp32) + stage P (bf16) for PV
        float* arow = Ab + (size_t)(q0 + w * 16 + lhi * 4) * S_ + (kt * BK + l15);
        #pragma unroll
        for (int c = 0; c < 4; ++c) {
            #pragma unroll
            for (int r = 0; r < 4; ++r) {
                float p = __expf(sacc[c][r]) * lsum[r];
                arow[(size_t)r * S_ + c * 16] = p;
                pbase[(lhi * 4 + r) * PSTR + c * 16 + l15] = f2bf(p);
            }
        }

        // PV: out += P (16x64) * V (64x128)
        #pragma unroll
        for (int ks = 0; ks < 2; ++ks) {
            bf16x8 pf = *(bf16x8*)&pbase[l15 * PSTR + ks * 32 + lhi * 8];
            #pragma unroll
            for (int d = 0; d < 8; ++d) {
                bf16x8 vf = *(bf16x8*)&Vlds[d * 16 + l15][ks * 32 + lhi * 8];
                oacc[d] = __builtin_amdgcn_mfma_f32_16x16x32_bf16(pf, vf, oacc[d], 0, 0, 0);
            }
        }
    }

    // ---- store out ----
    #pragma unroll
    for (int d = 0; d < 8; ++d) {
        #pragma unroll
        for (int r = 0; r < 4; ++r) {
            Ob[(size_t)(q0 + w * 16 + lhi * 4 + r) * D_ + d * 16 + l15] = oacc[d][r];
        }
    }
}

extern "C" void kernel_launch(void* const* d_in, const int* in_sizes, int n_in,
                              void* d_out, int out_size, void* d_ws, size_t ws_size,
                              hipStream_t stream) {
    const float* q = (const float*)d_in[0];
    const float* k = (const float*)d_in[1];
    const float* v = (const float*)d_in[2];
    float* out  = (float*)d_out;
    float* attn = out + (size_t)B_ * S_ * D_;   // outputs concatenated: (out, attn)

    dim3 grid(B_, S_ / BQ);   // batch fastest -> same-batch blocks share an XCD
    dim3 block(512);
    hipLaunchKernelGGL(attn_fused, grid, block, 0, stream, q, k, v, out, attn);
}